// Round 6
// baseline (215.591 us; speedup 1.0000x reference)
//
#include <hip/hip_runtime.h>
#include <hip/hip_bf16.h>
#include <math.h>

#define N_NODES 100000
#define N_EDGES 1600000
#define D 64
#define TWO_D 128
#define LN_EPS 1e-5f

#define BSHIFT 7                                   // 128 nodes per bucket
#define BMASK 127
#define NBUCK ((N_NODES + 127) >> BSHIFT)          // 782
#define EPB 4096                                   // edges per block (hist/scatter)
#define NEB ((N_EDGES + EPB - 1) / EPB)            // 391
#define STAGE_CAP 4096

typedef __attribute__((ext_vector_type(4))) float f32x4;
typedef __attribute__((ext_vector_type(8))) short bf16x8;
typedef __attribute__((ext_vector_type(8))) unsigned short u16x8;

__device__ __forceinline__ float b2f(unsigned short u) {
    return __uint_as_float(((unsigned)u) << 16);
}
__device__ __forceinline__ unsigned short f2b(float f) {
    __hip_bfloat16 h = __float2bfloat16(f);   // RNE
    return __builtin_bit_cast(unsigned short, h);
}

// ---------------------------------------------------------------------------
// CSR build, two-level counting sort (once per call; indices layer-invariant)
// Edge record packed to int32: (src << 7) | (dst & 127); src < 2^17.
// ---------------------------------------------------------------------------
__global__ __launch_bounds__(1024) void zero_kernel(int* __restrict__ p, int n) {
    int i = threadIdx.x;
    if (i < n) p[i] = 0;
}

__global__ __launch_bounds__(256) void bhist_kernel(const int* __restrict__ dst,
                                                    int* __restrict__ bcnt_g) {
    __shared__ int h[NBUCK];
    for (int i = threadIdx.x; i < NBUCK; i += 256) h[i] = 0;
    __syncthreads();
    const int e0 = blockIdx.x * EPB;
    const int e1 = min(e0 + EPB, N_EDGES);
    for (int e = e0 + threadIdx.x; e < e1; e += 256)
        atomicAdd(&h[dst[e] >> BSHIFT], 1);
    __syncthreads();
    for (int i = threadIdx.x; i < NBUCK; i += 256)
        if (h[i]) atomicAdd(&bcnt_g[i], h[i]);
}

__global__ __launch_bounds__(1024) void bscan_kernel(const int* __restrict__ bcnt_g,
                                                     int* __restrict__ bbase,
                                                     int* __restrict__ bcur) {
    __shared__ int lds[1024];
    int v = (threadIdx.x < NBUCK) ? bcnt_g[threadIdx.x] : 0;
    lds[threadIdx.x] = v;
    __syncthreads();
    for (int off = 1; off < 1024; off <<= 1) {
        int t = (threadIdx.x >= off) ? lds[threadIdx.x - off] : 0;
        __syncthreads();
        lds[threadIdx.x] += t;
        __syncthreads();
    }
    if (threadIdx.x < NBUCK) {
        int ex = lds[threadIdx.x] - v;     // exclusive
        bbase[threadIdx.x] = ex;
        bcur[threadIdx.x] = ex;
    }
    if (threadIdx.x == 0) bbase[NBUCK] = N_EDGES;
}

// Scatter packed edges into per-bucket contiguous regions.
__global__ __launch_bounds__(512) void bscat_kernel(const int* __restrict__ src,
                                                    const int* __restrict__ dst,
                                                    int* __restrict__ bcur,
                                                    int* __restrict__ ebuf) {
    __shared__ int h[NBUCK];
    __shared__ int base[NBUCK];
    for (int i = threadIdx.x; i < NBUCK; i += 512) h[i] = 0;
    __syncthreads();
    const int e0 = blockIdx.x * EPB;
    const int e1 = min(e0 + EPB, N_EDGES);
    for (int e = e0 + threadIdx.x; e < e1; e += 512)
        atomicAdd(&h[dst[e] >> BSHIFT], 1);
    __syncthreads();
    for (int i = threadIdx.x; i < NBUCK; i += 512) {
        int c = h[i];
        if (c) base[i] = atomicAdd(&bcur[i], c);
        h[i] = 0;
    }
    __syncthreads();
    for (int e = e0 + threadIdx.x; e < e1; e += 512) {
        int d = dst[e];
        int b = d >> BSHIFT;
        int r = atomicAdd(&h[b], 1);
        ebuf[base[b] + r] = (src[e] << BSHIFT) | (d & BMASK);
    }
}

// One block per bucket: LDS counting sort by node-within-bucket; emits
// row_ptr for its 128 nodes and streams ssrc out coalesced via an LDS stage.
__global__ __launch_bounds__(512) void bbuild_kernel(const int* __restrict__ ebuf,
                                                     const int* __restrict__ bbase,
                                                     int* __restrict__ row_ptr,
                                                     int* __restrict__ ssrc) {
    __shared__ int cnt[128];
    __shared__ int excl[128];
    __shared__ int stage[STAGE_CAP];
    const int b = blockIdx.x;
    const int nb0 = b << BSHIFT;
    const int bb = bbase[b], be = bbase[b + 1];
    const int bcnt = be - bb;

    if (threadIdx.x < 128) cnt[threadIdx.x] = 0;
    __syncthreads();
    for (int i = threadIdx.x; i < bcnt; i += 512)
        atomicAdd(&cnt[ebuf[bb + i] & BMASK], 1);
    __syncthreads();

    // exclusive scan of cnt -> excl (Hillis-Steele over 128)
    int v = (threadIdx.x < 128) ? cnt[threadIdx.x] : 0;
    if (threadIdx.x < 128) excl[threadIdx.x] = v;
    __syncthreads();
    for (int off = 1; off < 128; off <<= 1) {
        int t = 0;
        if (threadIdx.x < 128 && threadIdx.x >= off) t = excl[threadIdx.x - off];
        __syncthreads();
        if (threadIdx.x < 128) excl[threadIdx.x] += t;
        __syncthreads();
    }
    if (threadIdx.x < 128) {
        excl[threadIdx.x] -= v;            // inclusive -> exclusive
        int node = nb0 + threadIdx.x;
        if (node < N_NODES) row_ptr[node] = bb + excl[threadIdx.x];
        cnt[threadIdx.x] = 0;
    }
    if (b == 0 && threadIdx.x == 0) row_ptr[N_NODES] = N_EDGES;
    __syncthreads();

    if (bcnt <= STAGE_CAP) {
        for (int i = threadIdx.x; i < bcnt; i += 512) {
            int p = ebuf[bb + i];
            int dl = p & BMASK;
            int r = atomicAdd(&cnt[dl], 1);
            stage[excl[dl] + r] = p >> BSHIFT;
        }
        __syncthreads();
        for (int i = threadIdx.x; i < bcnt; i += 512)
            ssrc[bb + i] = stage[i];
    } else {   // fallback (degree skew) — correct, uncoalesced
        for (int i = threadIdx.x; i < bcnt; i += 512) {
            int p = ebuf[bb + i];
            int dl = p & BMASK;
            int r = atomicAdd(&cnt[dl], 1);
            ssrc[bb + excl[dl] + r] = p >> BSHIFT;
        }
    }
}

// ---------------------------------------------------------------------------
// Converters
// ---------------------------------------------------------------------------
__global__ __launch_bounds__(256) void cvt_x_kernel(const float* __restrict__ xf,
                                                    ushort* __restrict__ xb) {
    int i = blockIdx.x * 256 + threadIdx.x;            // one float4 each
    if (i < N_NODES * D / 4) {
        float4 v = ((const float4*)xf)[i];
        ushort4 o;
        o.x = f2b(v.x); o.y = f2b(v.y); o.z = f2b(v.z); o.w = f2b(v.w);
        ((ushort4*)xb)[i] = o;
    }
}

// Wperm[lay][s][c][lane][j] = bf16(W[lay][32s + 8*(lane>>4) + j][16c + (lane&15)])
__global__ __launch_bounds__(256) void cvt_w_kernel(const float* __restrict__ Ws,
                                                    ushort* __restrict__ Wperm) {
    int i = blockIdx.x * 256 + threadIdx.x;
    if (i >= 3 * 4 * 4 * 64 * 8) return;
    int j    = i & 7;
    int lane = (i >> 3) & 63;
    int c    = (i >> 9) & 3;
    int s    = (i >> 11) & 3;
    int lay  = i >> 13;
    int k = 32 * s + 8 * (lane >> 4) + j;
    int d = 16 * c + (lane & 15);
    Wperm[i] = f2b(Ws[((size_t)lay * TWO_D + k) * D + d]);
}

// ---------------------------------------------------------------------------
// Gather-max kernel: 8 lanes per node, lane owns ushort8 (16 B -> dwordx4
// loads). 8 nodes per wave. Register max, no atomics.
// agg = max(max_j x_src - x_dst, 0), stored bf16.
// ---------------------------------------------------------------------------
__global__ __launch_bounds__(256) void gather_kernel(
    const ushort* __restrict__ xb,
    const int* __restrict__ row_ptr,
    const int* __restrict__ ssrc,
    ushort* __restrict__ agg)
{
    const int node = blockIdx.x * 32 + (threadIdx.x >> 3);
    if (node >= N_NODES) return;
    const int fl = threadIdx.x & 7;
    const int base = threadIdx.x & 56;                 // 8-lane group base in wave
    const u16x8* __restrict__ x8 = (const u16x8*)xb;

    const u16x8 xs = x8[node * 8 + fl];

    const int beg = row_ptr[node], end = row_ptr[node + 1];
    float m[8];
#pragma unroll
    for (int e = 0; e < 8; ++e) m[e] = -INFINITY;

    for (int j = beg; j < end; j += 8) {
        const int cnt = min(end - j, 8);
        const int idx = ssrc[j + min(fl, cnt - 1)];
        int t = 0;
        if (t + 8 <= cnt) {
            int s0 = __shfl(idx, base,     64);
            int s1 = __shfl(idx, base + 1, 64);
            int s2 = __shfl(idx, base + 2, 64);
            int s3 = __shfl(idx, base + 3, 64);
            int s4 = __shfl(idx, base + 4, 64);
            int s5 = __shfl(idx, base + 5, 64);
            int s6 = __shfl(idx, base + 6, 64);
            int s7 = __shfl(idx, base + 7, 64);
            u16x8 r0 = x8[s0 * 8 + fl];
            u16x8 r1 = x8[s1 * 8 + fl];
            u16x8 r2 = x8[s2 * 8 + fl];
            u16x8 r3 = x8[s3 * 8 + fl];
            u16x8 r4 = x8[s4 * 8 + fl];
            u16x8 r5 = x8[s5 * 8 + fl];
            u16x8 r6 = x8[s6 * 8 + fl];
            u16x8 r7 = x8[s7 * 8 + fl];
#pragma unroll
            for (int e = 0; e < 8; ++e) {
                float v = fmaxf(fmaxf(fmaxf(b2f(r0[e]), b2f(r1[e])),
                                      fmaxf(b2f(r2[e]), b2f(r3[e]))),
                                fmaxf(fmaxf(b2f(r4[e]), b2f(r5[e])),
                                      fmaxf(b2f(r6[e]), b2f(r7[e]))));
                m[e] = fmaxf(m[e], v);
            }
            t = 8;
        }
        if (t + 4 <= cnt) {
            int s0 = __shfl(idx, base + t,     64);
            int s1 = __shfl(idx, base + t + 1, 64);
            int s2 = __shfl(idx, base + t + 2, 64);
            int s3 = __shfl(idx, base + t + 3, 64);
            u16x8 r0 = x8[s0 * 8 + fl];
            u16x8 r1 = x8[s1 * 8 + fl];
            u16x8 r2 = x8[s2 * 8 + fl];
            u16x8 r3 = x8[s3 * 8 + fl];
#pragma unroll
            for (int e = 0; e < 8; ++e) {
                float v = fmaxf(fmaxf(b2f(r0[e]), b2f(r1[e])),
                                fmaxf(b2f(r2[e]), b2f(r3[e])));
                m[e] = fmaxf(m[e], v);
            }
            t += 4;
        }
        for (; t < cnt; ++t) {
            int s0 = __shfl(idx, base + t, 64);
            u16x8 r0 = x8[s0 * 8 + fl];
#pragma unroll
            for (int e = 0; e < 8; ++e)
                m[e] = fmaxf(m[e], b2f(r0[e]));
        }
    }

    u16x8 o;
    if (end > beg) {
#pragma unroll
        for (int e = 0; e < 8; ++e)
            o[e] = f2b(fmaxf(m[e] - b2f(xs[e]), 0.f));
    } else {
#pragma unroll
        for (int e = 0; e < 8; ++e) o[e] = 0;
    }
    ((u16x8*)agg)[node * 8 + fl] = o;
}

// ---------------------------------------------------------------------------
// MFMA GEMM + bias + LayerNorm + ELU. Wave per 16 nodes, 16 MFMA.
// C-layout: col = 16c + (lane&15), row = 4*(lane>>4) + j.
// ---------------------------------------------------------------------------
__global__ __launch_bounds__(256) void gemm_kernel(
    const ushort* __restrict__ xb,
    const ushort* __restrict__ agg,
    const ushort* __restrict__ Wperm,   // this layer's [4][4][64][8]
    const float* __restrict__ bias,
    const float* __restrict__ gamma,
    const float* __restrict__ beta,
    ushort* __restrict__ out_b,         // bf16 out (layers 0,1) or nullptr
    float*  __restrict__ out_f)         // f32 out (layer 2) or nullptr
{
    const int wid = (blockIdx.x * 256 + threadIdx.x) >> 6;
    if (wid >= N_NODES / 16) return;
    const int lane = threadIdx.x & 63;
    const int n0 = wid * 16;
    const int row = lane & 15;
    const int kb  = lane >> 4;

    const bf16x8* __restrict__ wp = (const bf16x8*)Wperm;
    bf16x8 wf[4][4];
#pragma unroll
    for (int s = 0; s < 4; ++s)
#pragma unroll
        for (int c = 0; c < 4; ++c)
            wf[s][c] = wp[(s * 4 + c) * 64 + lane];

    const bf16x8* __restrict__ xv = (const bf16x8*)xb;
    const bf16x8* __restrict__ av = (const bf16x8*)agg;
    bf16x8 a0 = xv[(n0 + row) * 8 + kb];
    bf16x8 a1 = xv[(n0 + row) * 8 + 4 + kb];
    bf16x8 a2 = av[(n0 + row) * 8 + kb];
    bf16x8 a3 = av[(n0 + row) * 8 + 4 + kb];

    f32x4 acc[4];
#pragma unroll
    for (int c = 0; c < 4; ++c) acc[c] = (f32x4){0.f, 0.f, 0.f, 0.f};
#pragma unroll
    for (int c = 0; c < 4; ++c) {
        acc[c] = __builtin_amdgcn_mfma_f32_16x16x32_bf16(a0, wf[0][c], acc[c], 0, 0, 0);
        acc[c] = __builtin_amdgcn_mfma_f32_16x16x32_bf16(a1, wf[1][c], acc[c], 0, 0, 0);
        acc[c] = __builtin_amdgcn_mfma_f32_16x16x32_bf16(a2, wf[2][c], acc[c], 0, 0, 0);
        acc[c] = __builtin_amdgcn_mfma_f32_16x16x32_bf16(a3, wf[3][c], acc[c], 0, 0, 0);
    }

    float bv[4], gv[4], btv[4];
#pragma unroll
    for (int c = 0; c < 4; ++c) {
        const int col = 16 * c + row;
        bv[c] = bias[col]; gv[c] = gamma[col]; btv[c] = beta[col];
    }

#pragma unroll
    for (int j = 0; j < 4; ++j) {
        float h0 = acc[0][j] + bv[0];
        float h1 = acc[1][j] + bv[1];
        float h2 = acc[2][j] + bv[2];
        float h3 = acc[3][j] + bv[3];
        float ps = (h0 + h1) + (h2 + h3);
        ps += __shfl_xor(ps, 1, 64);
        ps += __shfl_xor(ps, 2, 64);
        ps += __shfl_xor(ps, 4, 64);
        ps += __shfl_xor(ps, 8, 64);
        const float mu = ps * (1.0f / 64.0f);
        const float d0 = h0 - mu, d1 = h1 - mu, d2 = h2 - mu, d3 = h3 - mu;
        float vs = (d0 * d0 + d1 * d1) + (d2 * d2 + d3 * d3);
        vs += __shfl_xor(vs, 1, 64);
        vs += __shfl_xor(vs, 2, 64);
        vs += __shfl_xor(vs, 4, 64);
        vs += __shfl_xor(vs, 8, 64);
        const float rstd = rsqrtf(vs * (1.0f / 64.0f) + LN_EPS);

        const int node = n0 + 4 * kb + j;
        const float dd[4] = {d0, d1, d2, d3};
#pragma unroll
        for (int c = 0; c < 4; ++c) {
            float o = dd[c] * rstd * gv[c] + btv[c];
            o = o > 0.f ? o : expm1f(o);
            if (out_f) out_f[node * D + 16 * c + row] = o;
            else       out_b[node * D + 16 * c + row] = f2b(o);
        }
    }
}

static inline size_t alignup(size_t v) { return (v + 255) & ~(size_t)255; }

extern "C" void kernel_launch(void* const* d_in, const int* in_sizes, int n_in,
                              void* d_out, int out_size, void* d_ws, size_t ws_size,
                              hipStream_t stream) {
    const float* features = (const float*)d_in[0];
    const int*   src      = (const int*)d_in[1];
    const int*   dst      = (const int*)d_in[2];
    const float* Ws       = (const float*)d_in[3];
    const float* bs       = (const float*)d_in[4];
    const float* gammas   = (const float*)d_in[5];
    const float* betas    = (const float*)d_in[6];
    float* out = (float*)d_out;

    char* ws = (char*)d_ws;
    size_t off = 0;
    int* row_ptr = (int*)(ws + off); off = alignup(off + sizeof(int) * (N_NODES + 1));
    int* bcnt_g  = (int*)(ws + off); off = alignup(off + sizeof(int) * NBUCK);
    int* bbase   = (int*)(ws + off); off = alignup(off + sizeof(int) * (NBUCK + 1));
    int* bcur    = (int*)(ws + off); off = alignup(off + sizeof(int) * NBUCK);
    int* ebuf    = (int*)(ws + off); off = alignup(off + sizeof(int) * (size_t)N_EDGES);
    int* ssrc    = (int*)(ws + off); off = alignup(off + sizeof(int) * N_EDGES);
    ushort* xbA  = (ushort*)(ws + off); off = alignup(off + sizeof(ushort) * (size_t)N_NODES * D);
    ushort* xbB  = (ushort*)(ws + off); off = alignup(off + sizeof(ushort) * (size_t)N_NODES * D);
    ushort* aggb = (ushort*)(ws + off); off = alignup(off + sizeof(ushort) * (size_t)N_NODES * D);
    ushort* Wperm= (ushort*)(ws + off); off = alignup(off + sizeof(ushort) * 3 * TWO_D * D);

    // --- build CSR (two-level counting sort, once) ---
    zero_kernel<<<1, 1024, 0, stream>>>(bcnt_g, NBUCK);
    bhist_kernel<<<NEB, 256, 0, stream>>>(dst, bcnt_g);
    bscan_kernel<<<1, 1024, 0, stream>>>(bcnt_g, bbase, bcur);
    bscat_kernel<<<NEB, 512, 0, stream>>>(src, dst, bcur, ebuf);
    bbuild_kernel<<<NBUCK, 512, 0, stream>>>(ebuf, bbase, row_ptr, ssrc);

    // --- converters ---
    cvt_x_kernel<<<(N_NODES * D / 4 + 255) / 256, 256, 0, stream>>>(features, xbA);
    cvt_w_kernel<<<(3 * 4 * 4 * 64 * 8 + 255) / 256, 256, 0, stream>>>(Ws, Wperm);

    // --- 3 layers ---
    const int g_blocks = (N_NODES + 31) / 32;          // 3125, 8-lane group/node
    const int m_blocks = (N_NODES / 16 + 3) / 4;       // 1563, wave/16-nodes

    ushort* xin = xbA;
    ushort* xnb[3] = { xbB, xbA, nullptr };
    for (int l = 0; l < 3; ++l) {
        gather_kernel<<<g_blocks, 256, 0, stream>>>(xin, row_ptr, ssrc, aggb);
        gemm_kernel<<<m_blocks, 256, 0, stream>>>(
            xin, aggb,
            Wperm + (size_t)l * 16 * 64 * 8,
            bs + (size_t)l * D,
            gammas + (size_t)l * D,
            betas + (size_t)l * D,
            xnb[l],
            (l == 2) ? out : nullptr);
        xin = xnb[l];
    }
}